// Round 4
// baseline (930.040 us; speedup 1.0000x reference)
//
#include <hip/hip_runtime.h>
#include <hip/hip_bf16.h>
#include <math.h>

// Problem constants
#define V_  32000
#define D_  512
#define DFF_ 2048
#define L_  4
#define H_  8
#define N_  64
#define K_  8
#define NB_ 32
#define R_  64
#define B_  2
#define S_  512
#define T_  1024   // B*S
#define DH_ 64

typedef short bhalf8 __attribute__((ext_vector_type(8)));
typedef float floatx4 __attribute__((ext_vector_type(4)));

#define GLOAD16(gp, lp) __builtin_amdgcn_global_load_lds( \
    (const __attribute__((address_space(1))) void*)(gp), \
    (__attribute__((address_space(3))) void*)(lp), 16, 0, 0)

__device__ __forceinline__ float gelu_f(float v) {
    return 0.5f * v * (1.0f + erff(v * 0.70710678118654752f));
}

__device__ __forceinline__ unsigned pk2(float a, float b) {
    unsigned ua = (unsigned)__bfloat16_as_ushort(__float2bfloat16(a));
    unsigned ub = (unsigned)__bfloat16_as_ushort(__float2bfloat16(b));
    return ua | (ub << 16);
}

// ------------------------------------------------------------- MFMA GEMM
// C[M,N] = A[M,K] @ Bt[N,K]^T (+bias). A,Bt bf16 row-major. 256 threads,
// 4 waves WRxWC. BK=64, double-buffered LDS, XOR-swizzle (16B unit u^=row&7).
// EPI: 0=f32 store, 1=bf16 store, 2=bf16 gelu, 3=xf (bf16(aux + bias[0]*acc)),
//      4=f32 accumulate (C += acc + bias).
// SWAP: blockIdx.x indexes M-tiles (for B-panel L2/L3 reuse on wide-N GEMMs).
template<int BM, int BN, int WR, int WC, int EPI, bool SWAP = false>
__global__ __launch_bounds__(256) void gemm_mfma(
    const __hip_bfloat16* __restrict__ A, int lda, long sA,
    const __hip_bfloat16* __restrict__ Bt, int ldb, long sB,
    const float* __restrict__ bias,
    const float* __restrict__ aux,
    void* __restrict__ Cv, int ldc, long sC,
    int Kdim)
{
    constexpr int FM = BM / WR / 16;
    constexpr int FN = BN / WC / 16;
    constexpr int ACH = BM * 8;   // 16B chunks per A K-tile
    constexpr int BCH = BN * 8;
    __shared__ __align__(16) short As[2][BM * 64];
    __shared__ __align__(16) short Bs[2][BN * 64];
    const int tid = threadIdx.x;
    const int z = blockIdx.z;
    A  += (long)z * sA;
    Bt += (long)z * sB;
    const int bm = (SWAP ? blockIdx.x : blockIdx.y) * BM;
    const int bn = (SWAP ? blockIdx.y : blockIdx.x) * BN;
    const int w = tid >> 6, lane = tid & 63;
    const int wr = w / WC, wc = w % WC;
    const int moff = wr * (BM / WR), noff = wc * (BN / WC);
    floatx4 acc[FM][FN] = {};

    auto stage = [&](int buf, int k0) {
        #pragma unroll
        for (int i = 0; i < ACH / 256; i++) {
            int c = tid + i * 256;
            int m = c >> 3, u = (c & 7) ^ (m & 7);     // pre-swizzled source
            const __hip_bfloat16* src = A + (long)(bm + m) * lda + k0 + u * 8;
            char* dst = (char*)&As[buf][0] + (w * 64 + i * 256) * 16;
            GLOAD16(src, dst);
        }
        #pragma unroll
        for (int i = 0; i < BCH / 256; i++) {
            int c = tid + i * 256;
            int m = c >> 3, u = (c & 7) ^ (m & 7);
            const __hip_bfloat16* src = Bt + (long)(bn + m) * ldb + k0 + u * 8;
            char* dst = (char*)&Bs[buf][0] + (w * 64 + i * 256) * 16;
            GLOAD16(src, dst);
        }
    };

    const int nt = Kdim >> 6;
    stage(0, 0);
    __syncthreads();
    int cur = 0;
    for (int t = 0; t < nt; ++t) {
        if (t + 1 < nt) stage(cur ^ 1, (t + 1) * 64);   // prefetch flies under MFMA
        #pragma unroll
        for (int kk = 0; kk < 2; kk++) {
            bhalf8 af[FM], bf[FN];
            #pragma unroll
            for (int fm = 0; fm < FM; fm++) {
                int row = moff + fm * 16 + (lane & 15);
                int u = (kk * 4 + (lane >> 4)) ^ (row & 7);
                af[fm] = *(const bhalf8*)((const char*)&As[cur][0] + row * 128 + u * 16);
            }
            #pragma unroll
            for (int fn = 0; fn < FN; fn++) {
                int row = noff + fn * 16 + (lane & 15);
                int u = (kk * 4 + (lane >> 4)) ^ (row & 7);
                bf[fn] = *(const bhalf8*)((const char*)&Bs[cur][0] + row * 128 + u * 16);
            }
            #pragma unroll
            for (int fm = 0; fm < FM; fm++)
                #pragma unroll
                for (int fn = 0; fn < FN; fn++)
                    acc[fm][fn] = __builtin_amdgcn_mfma_f32_16x16x32_bf16(
                        af[fm], bf[fn], acc[fm][fn], 0, 0, 0);
        }
        __syncthreads();   // drains vmcnt: next tile landed during compute
        cur ^= 1;
    }

    float* Cf = (float*)Cv;
    __hip_bfloat16* Cb = (__hip_bfloat16*)Cv;
    const long zoff = (long)z * sC;
    const int lr = lane >> 4, lc = lane & 15;
    float alphaV = (EPI == 3) ? bias[0] : 0.f;
    #pragma unroll
    for (int fm = 0; fm < FM; fm++) {
        #pragma unroll
        for (int fn = 0; fn < FN; fn++) {
            int cN = bn + noff + fn * 16 + lc;
            float bv = (EPI == 3 || !bias) ? 0.f : bias[cN];
            #pragma unroll
            for (int i = 0; i < 4; i++) {
                int rM = bm + moff + fm * 16 + lr * 4 + i;
                long idx = zoff + (long)rM * ldc + cN;
                float v = acc[fm][fn][i] + bv;
                if constexpr (EPI == 0) Cf[idx] = v;
                else if constexpr (EPI == 1) Cb[idx] = __float2bfloat16(v);
                else if constexpr (EPI == 2) Cb[idx] = __float2bfloat16(gelu_f(v));
                else if constexpr (EPI == 3)
                    Cb[idx] = __float2bfloat16(aux[idx] + alphaV * acc[fm][fn][i]);
                else if constexpr (EPI == 4) Cf[idx] += v;
            }
        }
    }
}

// --------------------------------------------------- scores GEMM + top-k route
// scores[64 tok][64 n] = qry @ ne^T, then per-token top-8 softmax -> tr[t][32].
__global__ __launch_bounds__(256) void score_route(
    const __hip_bfloat16* __restrict__ A,     // qryB [1024][512]
    const __hip_bfloat16* __restrict__ Bt,    // neB  [64][512]
    const float* __restrict__ sel,            // [64][32]
    float* __restrict__ tr)                   // [1024][32]
{
    constexpr int BM = 64, BN = 64;
    __shared__ __align__(16) short As[2][BM * 64];
    __shared__ __align__(16) short Bs[2][BN * 64];
    __shared__ float sc[64][66];
    const int tid = threadIdx.x;
    const int bm = blockIdx.x * BM;
    const int w = tid >> 6, lane = tid & 63;
    const int wr = w >> 1, wc = w & 1;
    const int moff = wr * 32, noff = wc * 32;
    floatx4 acc[2][2] = {};

    auto stage = [&](int buf, int k0) {
        #pragma unroll
        for (int i = 0; i < 2; i++) {
            int c = tid + i * 256;
            int m = c >> 3, u = (c & 7) ^ (m & 7);
            GLOAD16(A + (long)(bm + m) * 512 + k0 + u * 8,
                    (char*)&As[buf][0] + (w * 64 + i * 256) * 16);
        }
        #pragma unroll
        for (int i = 0; i < 2; i++) {
            int c = tid + i * 256;
            int m = c >> 3, u = (c & 7) ^ (m & 7);
            GLOAD16(Bt + (long)m * 512 + k0 + u * 8,
                    (char*)&Bs[buf][0] + (w * 64 + i * 256) * 16);
        }
    };

    stage(0, 0);
    __syncthreads();
    int cur = 0;
    for (int t = 0; t < 8; ++t) {
        if (t < 7) stage(cur ^ 1, (t + 1) * 64);
        #pragma unroll
        for (int kk = 0; kk < 2; kk++) {
            bhalf8 af[2], bf[2];
            #pragma unroll
            for (int fm = 0; fm < 2; fm++) {
                int row = moff + fm * 16 + (lane & 15);
                int u = (kk * 4 + (lane >> 4)) ^ (row & 7);
                af[fm] = *(const bhalf8*)((const char*)&As[cur][0] + row * 128 + u * 16);
            }
            #pragma unroll
            for (int fn = 0; fn < 2; fn++) {
                int row = noff + fn * 16 + (lane & 15);
                int u = (kk * 4 + (lane >> 4)) ^ (row & 7);
                bf[fn] = *(const bhalf8*)((const char*)&Bs[cur][0] + row * 128 + u * 16);
            }
            #pragma unroll
            for (int fm = 0; fm < 2; fm++)
                #pragma unroll
                for (int fn = 0; fn < 2; fn++)
                    acc[fm][fn] = __builtin_amdgcn_mfma_f32_16x16x32_bf16(
                        af[fm], bf[fn], acc[fm][fn], 0, 0, 0);
        }
        __syncthreads();
        cur ^= 1;
    }
    const int lr = lane >> 4, lc = lane & 15;
    #pragma unroll
    for (int fm = 0; fm < 2; fm++)
        #pragma unroll
        for (int fn = 0; fn < 2; fn++)
            #pragma unroll
            for (int i = 0; i < 4; i++)
                sc[moff + fm * 16 + lr * 4 + i][noff + fn * 16 + lc] = acc[fm][fn][i];
    __syncthreads();
    // each wave: 16 tokens, top-8 over 64 scores
    for (int it = 0; it < 16; it++) {
        int row = w * 16 + it;
        float myval = sc[row][lane];
        float topv[K_]; int topi[K_];
        #pragma unroll
        for (int kk = 0; kk < K_; kk++) {
            float v = myval; int idx = lane;
            #pragma unroll
            for (int off = 32; off; off >>= 1) {
                float ov = __shfl_down(v, off);
                int oi = __shfl_down(idx, off);
                if (ov > v || (ov == v && oi < idx)) { v = ov; idx = oi; }
            }
            v = __shfl(v, 0); idx = __shfl(idx, 0);
            topv[kk] = v; topi[kk] = idx;
            if (lane == idx) myval = -INFINITY;
        }
        float mx = topv[0];
        float wt[K_], sum = 0.f;
        #pragma unroll
        for (int kk = 0; kk < K_; kk++) { wt[kk] = expf(topv[kk] - mx); sum += wt[kk]; }
        float inv = 1.f / sum;
        if (lane < NB_) {
            float a = 0.f;
            #pragma unroll
            for (int kk = 0; kk < K_; kk++) a += wt[kk] * inv * sel[topi[kk] * NB_ + lane];
            tr[(long)(bm + row) * NB_ + lane] = a;
        }
    }
}

// ------------------------------------------------------------- flash attention
__global__ __launch_bounds__(256) void attn_mfma(
    const __hip_bfloat16* __restrict__ qkv,
    const __hip_bfloat16* __restrict__ vt,
    __hip_bfloat16* __restrict__ catB)
{
    __shared__ short pbuf[4][16][72];
    const int tid = threadIdx.x;
    const int w = tid >> 6, lane = tid & 63;
    const int g = lane >> 4, ql = lane & 15;
    const int h = blockIdx.y, b = blockIdx.z;
    const int qbase = blockIdx.x * 64 + w * 16;

    const long qrow = ((long)(b * S_ + qbase + ql)) * 1536 + h * DH_;
    bhalf8 qa0 = *(const bhalf8*)(qkv + qrow + g * 8);
    bhalf8 qa1 = *(const bhalf8*)(qkv + qrow + 32 + g * 8);
    const __hip_bfloat16* kB = qkv + 512;
    const __hip_bfloat16* vbase = vt + ((long)(b * H_ + h)) * DH_ * S_;

    floatx4 o[4] = {};
    float m = -INFINITY, ls = 0.f;
    const float SC = 0.125f * 1.44269504088896f;
    const int nblk = blockIdx.x + 1;

    for (int kvb = 0; kvb < nblk; kvb++) {
        const int kb0 = kvb * 64;
        floatx4 st[4];
        #pragma unroll
        for (int t = 0; t < 4; t++) {
            long krow = ((long)(b * S_ + kb0 + t * 16 + ql)) * 1536 + h * DH_;
            bhalf8 ka0 = *(const bhalf8*)(kB + krow + g * 8);
            bhalf8 ka1 = *(const bhalf8*)(kB + krow + 32 + g * 8);
            floatx4 z = {};
            z = __builtin_amdgcn_mfma_f32_16x16x32_bf16(ka0, qa0, z, 0, 0, 0);
            z = __builtin_amdgcn_mfma_f32_16x16x32_bf16(ka1, qa1, z, 0, 0, 0);
            st[t] = z;
        }
        const int q = qbase + ql;
        float p[4][4];
        float m4 = -INFINITY;
        #pragma unroll
        for (int t = 0; t < 4; t++)
            #pragma unroll
            for (int i = 0; i < 4; i++) {
                int kv = kb0 + t * 16 + g * 4 + i;
                float v = (kv <= q) ? st[t][i] * SC : -INFINITY;
                p[t][i] = v; m4 = fmaxf(m4, v);
            }
        m4 = fmaxf(m4, __shfl_xor(m4, 16));
        m4 = fmaxf(m4, __shfl_xor(m4, 32));
        float mnew = fmaxf(m, m4);
        float corr = exp2f(m - mnew);
        m = mnew;
        float lsum = 0.f;
        #pragma unroll
        for (int t = 0; t < 4; t++)
            #pragma unroll
            for (int i = 0; i < 4; i++) {
                float e = exp2f(p[t][i] - mnew);
                p[t][i] = e; lsum += e;
            }
        lsum += __shfl_xor(lsum, 16);
        lsum += __shfl_xor(lsum, 32);
        ls = ls * corr + lsum;
        unsigned* prow = (unsigned*)&pbuf[w][ql][0];
        #pragma unroll
        for (int t = 0; t < 4; t++) {
            prow[t * 8 + g * 2]     = pk2(p[t][0], p[t][1]);
            prow[t * 8 + g * 2 + 1] = pk2(p[t][2], p[t][3]);
        }
        #pragma unroll
        for (int i = 0; i < 4; i++) {
            float c = __shfl(corr, g * 4 + i);
            #pragma unroll
            for (int dt = 0; dt < 4; dt++) o[dt][i] *= c;
        }
        __syncthreads();
        #pragma unroll
        for (int ks = 0; ks < 2; ks++) {
            bhalf8 pa = *(const bhalf8*)&pbuf[w][ql][ks * 32 + g * 8];
            #pragma unroll
            for (int dt = 0; dt < 4; dt++) {
                bhalf8 vb = *(const bhalf8*)(vbase + (long)(dt * 16 + ql) * S_ + kb0 + ks * 32 + g * 8);
                o[dt] = __builtin_amdgcn_mfma_f32_16x16x32_bf16(pa, vb, o[dt], 0, 0, 0);
            }
        }
        __syncthreads();
    }
    const float inv = 1.f / ls;
    #pragma unroll
    for (int i = 0; i < 4; i++) {
        float iv = __shfl(inv, g * 4 + i);
        int trow = b * S_ + qbase + g * 4 + i;
        #pragma unroll
        for (int dt = 0; dt < 4; dt++)
            catB[(long)trow * 1024 + 512 + h * DH_ + dt * 16 + ql] =
                __float2bfloat16(o[dt][i] * iv);
    }
}

__global__ __launch_bounds__(256) void vtrans(const __hip_bfloat16* __restrict__ qkv,
                                              __hip_bfloat16* __restrict__ vt) {
    __shared__ short tl[32][33];
    int bh = blockIdx.z; int b = bh >> 3, h = bh & 7;
    int s0 = blockIdx.x * 32, d0 = blockIdx.y * 32;
    int tx = threadIdx.x & 31, ty = threadIdx.x >> 5;
    #pragma unroll
    for (int r = 0; r < 4; r++)
        tl[ty * 4 + r][tx] = *(const short*)(qkv + (long)(b * S_ + s0 + ty * 4 + r) * 1536
                                             + 1024 + h * DH_ + d0 + tx);
    __syncthreads();
    #pragma unroll
    for (int r = 0; r < 4; r++)
        *(short*)(vt + (long)bh * DH_ * S_ + (long)(d0 + ty * 4 + r) * S_ + s0 + tx)
            = tl[tx][ty * 4 + r];
}

// ------------------------------------------------------------- conversions
__global__ __launch_bounds__(256) void tcvt(const float* __restrict__ in, int ldn, long sIn,
                                            __hip_bfloat16* __restrict__ out, int ldk, long sOut) {
    __shared__ float t[32][33];
    in  += (long)blockIdx.z * sIn;
    out += (long)blockIdx.z * sOut;
    int k0 = blockIdx.y * 32, n0 = blockIdx.x * 32;
    int tx = threadIdx.x & 31, ty = threadIdx.x >> 5;
    #pragma unroll
    for (int r = 0; r < 4; r++) t[ty * 4 + r][tx] = in[(long)(k0 + ty * 4 + r) * ldn + n0 + tx];
    __syncthreads();
    #pragma unroll
    for (int r = 0; r < 4; r++)
        out[(long)(n0 + ty * 4 + r) * ldk + k0 + tx] = __float2bfloat16(t[tx][ty * 4 + r]);
}

__global__ void cvt_temb(const float* __restrict__ in, __hip_bfloat16* __restrict__ out) {
    long i = ((long)blockIdx.x * 256 + threadIdx.x) * 4;
    float4 v = *(const float4*)(in + i);
    out[i]     = __float2bfloat16(v.x);
    out[i + 1] = __float2bfloat16(v.y);
    out[i + 2] = __float2bfloat16(v.z);
    out[i + 3] = __float2bfloat16(v.w);
}

__global__ void basis_prep(const float* __restrict__ A,
                           __hip_bfloat16* __restrict__ projT,
                           __hip_bfloat16* __restrict__ deltaT) {
    long i = (long)blockIdx.x * 256 + threadIdx.x;
    if (i >= (long)NB_ * D_ * R_) return;
    int r = i & 63; int d = (i >> 6) & 511; int n = i >> 15;
    __hip_bfloat16 v = __float2bfloat16(A[i]);
    projT[((long)n * R_ + r) * D_ + d] = v;
    deltaT[(long)d * (NB_ * R_) + n * R_ + r] = v;
}

__global__ void bias_cat(const float* __restrict__ bq, const float* __restrict__ bk,
                         const float* __restrict__ bv, float* __restrict__ o) {
    int i = blockIdx.x * 256 + threadIdx.x;
    int l = i / 1536, j = i % 1536;
    float v = (j < 512) ? bq[l * 512 + j] : (j < 1024) ? bk[l * 512 + j - 512]
                                                       : bv[l * 512 + j - 1024];
    o[i] = v;
}

// ------------------------------------------------------------- helpers
__global__ void embed_kernel(const int* __restrict__ ids, const float* __restrict__ temb,
                             const float* __restrict__ pemb, float* __restrict__ x) {
    int t = blockIdx.x;
    int s = t % S_;
    int id = ids[t];
    for (int d = threadIdx.x; d < D_; d += blockDim.x)
        x[(long)t * D_ + d] = temb[(long)id * D_ + d] + pemb[(long)s * D_ + d];
}

__global__ __launch_bounds__(256) void ln_kernel(const float* __restrict__ in,
                                                 const float* __restrict__ g,
                                                 const float* __restrict__ b,
                                                 float* __restrict__ outf,
                                                 __hip_bfloat16* __restrict__ outb, int ldo) {
    int t = blockIdx.x;
    const float* row = in + (long)t * D_;
    int tid = threadIdx.x;
    float v0 = row[tid], v1 = row[tid + 256];
    __shared__ float red[256];
    red[tid] = v0 + v1; __syncthreads();
    for (int off = 128; off; off >>= 1) { if (tid < off) red[tid] += red[tid + off]; __syncthreads(); }
    float mean = red[0] * (1.0f / D_); __syncthreads();
    float d0 = v0 - mean, d1 = v1 - mean;
    red[tid] = d0 * d0 + d1 * d1; __syncthreads();
    for (int off = 128; off; off >>= 1) { if (tid < off) red[tid] += red[tid + off]; __syncthreads(); }
    float rstd = rsqrtf(red[0] * (1.0f / D_) + 1e-5f);
    float o0 = d0 * rstd * g[tid]       + b[tid];
    float o1 = d1 * rstd * g[tid + 256] + b[tid + 256];
    if (outf) {
        outf[(long)t * D_ + tid]       = o0;
        outf[(long)t * D_ + tid + 256] = o1;
    }
    outb[(long)t * ldo + tid]       = __float2bfloat16(o0);
    outb[(long)t * ldo + tid + 256] = __float2bfloat16(o1);
}

__global__ void ne_kernel(const float* __restrict__ rec, const float* __restrict__ bemb,
                          __hip_bfloat16* __restrict__ neb, float* __restrict__ sel) {
    int n = blockIdx.x;
    __shared__ float w[NB_];
    if (threadIdx.x == 0) {
        float mx = -1e30f;
        for (int i = 0; i < NB_; i++) mx = fmaxf(mx, rec[n * NB_ + i]);
        float sm = 0.f;
        for (int i = 0; i < NB_; i++) { float e = expf(rec[n * NB_ + i] - mx); w[i] = e; sm += e; }
        float inv = 1.f / sm;
        for (int i = 0; i < NB_; i++) w[i] *= inv;
    }
    __syncthreads();
    if (threadIdx.x < NB_) sel[n * NB_ + threadIdx.x] = w[threadIdx.x];
    for (int d = threadIdx.x; d < D_; d += blockDim.x) {
        float acc = 0.f;
        #pragma unroll
        for (int nb = 0; nb < NB_; nb++) acc += w[nb] * bemb[nb * D_ + d];
        neb[(long)n * D_ + d] = __float2bfloat16(acc);
    }
}

// h[r] = sum_n tr[n]*proj[t][n*64+r]; g[t][n*64+r] = bf16(tr[n]*h[r])
__global__ __launch_bounds__(256) void hg_kernel(const float* __restrict__ tr,
                                                 const float* __restrict__ P,
                                                 __hip_bfloat16* __restrict__ g) {
    int t = blockIdx.x, tid = threadIdx.x;
    __shared__ float hl[64];
    __shared__ float trl[32];
    if (tid < 32) trl[tid] = tr[(long)t * 32 + tid];
    __syncthreads();
    if (tid < 64) {
        float acc = 0.f;
        const float* p = P + (long)t * 2048 + tid;
        #pragma unroll
        for (int n = 0; n < 32; n++) acc += trl[n] * p[n * 64];
        hl[tid] = acc;
    }
    __syncthreads();
    #pragma unroll
    for (int j = 0; j < 8; j++) {
        int idx = tid * 8 + j;
        int n = idx >> 6, r = idx & 63;
        g[(long)t * 2048 + idx] = __float2bfloat16(trl[n] * hl[r]);
    }
}

// ------------------------------------------------------------- launch
extern "C" void kernel_launch(void* const* d_in, const int* in_sizes, int n_in,
                              void* d_out, int out_size, void* d_ws, size_t ws_size,
                              hipStream_t stream) {
    const int*   ids    = (const int*)d_in[0];
    const float* temb   = (const float*)d_in[1];
    const float* pemb   = (const float*)d_in[2];
    const float* basisA = (const float*)d_in[3];
    const float* bemb   = (const float*)d_in[4];
    const float* recipe = (const float*)d_in[5];
    const float* Wq = (const float*)d_in[6],  *bq = (const float*)d_in[7];
    const float* Wk = (const float*)d_in[8],  *bk = (const float*)d_in[9];
    const float* Wv = (const float*)d_in[10], *bv = (const float*)d_in[11];
    const float* Ws = (const float*)d_in[12], *bs = (const float*)d_in[13];
    const float* Wup = (const float*)d_in[14], *bup = (const float*)d_in[15];
    const float* Wdn = (const float*)d_in[16], *bdn = (const float*)d_in[17];
    const float* ln1g = (const float*)d_in[18], *ln1b = (const float*)d_in[19];
    const float* ln2g = (const float*)d_in[20], *ln2b = (const float*)d_in[21];
    const float* alpha = (const float*)d_in[22];
    const float* lnfg = (const float*)d_in[23], *lnfb = (const float*)d_in[24];
    float* out = (float*)d_out;
    float* W = (float*)d_ws;

    // fp32 arena (float offsets)
    float* x    = W + 0;          // 524288
    float* buf1 = W + 524288;     // n2 f32 (xf input)
    float* trb  = W + 1114112;    // 32768
    float* sel  = W + 1212416;    // 2048
    float* P    = W + 1214464;    // proj f32 2097152
    float* bqkv = W + 3835904;    // 6144
    // bf16 arena
    __hip_bfloat16* SB = (__hip_bfloat16*)(W + 3844096);
    __hip_bfloat16* tembB  = SB + 0;          // 16384000
    __hip_bfloat16* qkvT   = SB + 16384000;   // 3145728
    __hip_bfloat16* WsT    = SB + 19529728;   // 2097152
    __hip_bfloat16* WupT   = SB + 21626880;   // 4194304
    __hip_bfloat16* WdnT   = SB + 25821184;   // 4194304
    __hip_bfloat16* projT  = SB + 30015488;   // 1048576
    __hip_bfloat16* deltaT = SB + 31064064;   // 1048576
    __hip_bfloat16* neB    = SB + 32112640;   // 32768
    __hip_bfloat16* catB   = SB + 32145408;   // 1048576
    __hip_bfloat16* qryB   = SB + 33193984;   // 524288
    __hip_bfloat16* n2B    = SB + 33718272;   // 524288
    __hip_bfloat16* xfB    = SB + 34242560;   // 524288
    __hip_bfloat16* gB     = SB + 34766848;   // 2097152
    __hip_bfloat16* ffhB   = SB + 36864000;   // 2097152
    __hip_bfloat16* qkvB   = SB + 38961152;   // 1572864
    __hip_bfloat16* VtB    = SB + 40534016;   // 524288

    dim3 blk(256);
    // ---- one-time conversions ----
    cvt_temb<<<16000, blk, 0, stream>>>(temb, tembB);
    basis_prep<<<4096, blk, 0, stream>>>(basisA, projT, deltaT);
    bias_cat<<<24, blk, 0, stream>>>(bq, bk, bv, bqkv);
    tcvt<<<dim3(16, 16, 4), blk, 0, stream>>>(Wq, D_, (long)D_ * D_, qkvT, D_, (long)1536 * D_);
    tcvt<<<dim3(16, 16, 4), blk, 0, stream>>>(Wk, D_, (long)D_ * D_, qkvT + 512 * 512, D_, (long)1536 * D_);
    tcvt<<<dim3(16, 16, 4), blk, 0, stream>>>(Wv, D_, (long)D_ * D_, qkvT + 1024 * 512, D_, (long)1536 * D_);
    tcvt<<<dim3(16, 32, 4), blk, 0, stream>>>(Ws, D_, (long)2 * D_ * D_, WsT, 2 * D_, (long)2 * D_ * D_);
    tcvt<<<dim3(64, 16, 4), blk, 0, stream>>>(Wup, DFF_, (long)D_ * DFF_, WupT, D_, (long)D_ * DFF_);
    tcvt<<<dim3(16, 64, 4), blk, 0, stream>>>(Wdn, D_, (long)DFF_ * D_, WdnT, DFF_, (long)DFF_ * D_);
    embed_kernel<<<T_, blk, 0, stream>>>(ids, temb, pemb, x);

    for (int l = 0; l < L_; l++) {
        ne_kernel<<<N_, blk, 0, stream>>>(recipe + (long)l * N_ * NB_, bemb, neB, sel);
        ln_kernel<<<T_, blk, 0, stream>>>(x, ln1g + l * D_, ln1b + l * D_, nullptr, catB, 1024);
        // fused QKV: [1024,1536] bf16
        gemm_mfma<64, 64, 2, 2, 1><<<dim3(24, 16), blk, 0, stream>>>(
            catB, 1024, 0, qkvT + (long)l * 1536 * 512, D_, 0, bqkv + l * 1536, nullptr,
            qkvB, 1536, 0, D_);
        vtrans<<<dim3(16, 2, 16), blk, 0, stream>>>(qkvB, VtB);
        attn_mfma<<<dim3(8, H_, B_), blk, 0, stream>>>(qkvB, VtB, catB);
        // query = cat @ Ws + bs -> bf16
        gemm_mfma<64, 64, 2, 2, 1><<<dim3(8, 16), blk, 0, stream>>>(
            catB, 2 * D_, 0, WsT + (long)l * 2 * D_ * D_, 2 * D_, 0, bs + l * D_, nullptr,
            qryB, D_, 0, 2 * D_);
        // scores + top-k route fused
        score_route<<<16, blk, 0, stream>>>(qryB, neB, sel, trb);
        ln_kernel<<<T_, blk, 0, stream>>>(x, ln2g + l * D_, ln2b + l * D_, buf1, n2B, 512);
        // proj: batched over n (z=32)
        gemm_mfma<128, 64, 2, 2, 0><<<dim3(1, 8, NB_), blk, 0, stream>>>(
            n2B, D_, 0, projT, D_, (long)R_ * D_, nullptr, nullptr, P, NB_ * R_, R_, D_);
        hg_kernel<<<T_, blk, 0, stream>>>(trb, P, gB);
        // delta GEMM + fused xf: xfB = bf16(n2 + alpha*delta)
        gemm_mfma<64, 64, 2, 2, 3><<<dim3(8, 16), blk, 0, stream>>>(
            gB, NB_ * R_, 0, deltaT, NB_ * R_, 0, alpha + l, buf1,
            xfB, D_, 0, NB_ * R_);
        // FFN up (+gelu, bf16 out)
        gemm_mfma<64, 64, 2, 2, 2><<<dim3(32, 16), blk, 0, stream>>>(
            xfB, D_, 0, WupT + (long)l * D_ * DFF_, D_, 0, bup + l * DFF_, nullptr,
            ffhB, DFF_, 0, D_);
        // FFN down fused residual: x += down + bias
        gemm_mfma<64, 64, 2, 2, 4><<<dim3(8, 16), blk, 0, stream>>>(
            ffhB, DFF_, 0, WdnT + (long)l * DFF_ * D_, DFF_, 0, bdn + l * D_, nullptr,
            x, D_, 0, DFF_);
    }
    // final LN + tied head (SWAP grid: 8 row-tiles fastest for B-panel reuse)
    ln_kernel<<<T_, blk, 0, stream>>>(x, lnfg, lnfb, nullptr, n2B, 512);
    gemm_mfma<128, 128, 2, 2, 0, true><<<dim3(8, 250), blk, 0, stream>>>(
        n2B, D_, 0, tembB, D_, 0, nullptr, nullptr, out, V_, 0, D_);
}

// Round 5
// 667.638 us; speedup vs baseline: 1.3930x; 1.3930x over previous
//
#include <hip/hip_runtime.h>
#include <hip/hip_bf16.h>
#include <math.h>

// Problem constants
#define V_  32000
#define D_  512
#define DFF_ 2048
#define L_  4
#define H_  8
#define N_  64
#define K_  8
#define NB_ 32
#define R_  64
#define B_  2
#define S_  512
#define T_  1024   // B*S
#define DH_ 64

typedef short bhalf8 __attribute__((ext_vector_type(8)));
typedef float floatx4 __attribute__((ext_vector_type(4)));

#define GLOAD16(gp, lp) __builtin_amdgcn_global_load_lds( \
    (const __attribute__((address_space(1))) void*)(gp), \
    (__attribute__((address_space(3))) void*)(lp), 16, 0, 0)

__device__ __forceinline__ float gelu_f(float v) {
    return 0.5f * v * (1.0f + erff(v * 0.70710678118654752f));
}

__device__ __forceinline__ unsigned pk2(float a, float b) {
    unsigned ua = (unsigned)__bfloat16_as_ushort(__float2bfloat16(a));
    unsigned ub = (unsigned)__bfloat16_as_ushort(__float2bfloat16(b));
    return ua | (ub << 16);
}

// ------------------------------------------------------------- MFMA GEMM
// C[M,N] = A[M,K] @ Bt[N,K]^T (+bias). A,Bt bf16 row-major. 256 threads,
// 4 waves WRxWC. BK=64, double-buffered LDS, XOR-swizzle (16B unit u^=row&7).
// EPI: 0=f32 store, 1=bf16 store, 2=bf16 gelu, 3=xf (bf16(aux + bias[0]*acc)),
//      4=f32 accumulate (C += acc + bias).
// SWAP: blockIdx.x indexes M-tiles (for B-panel L2/L3 reuse on wide-N GEMMs).
template<int BM, int BN, int WR, int WC, int EPI, bool SWAP = false>
__global__ __launch_bounds__(256) void gemm_mfma(
    const __hip_bfloat16* __restrict__ A, int lda, long sA,
    const __hip_bfloat16* __restrict__ Bt, int ldb, long sB,
    const float* __restrict__ bias,
    const float* __restrict__ aux,
    void* __restrict__ Cv, int ldc, long sC,
    int Kdim)
{
    constexpr int FM = BM / WR / 16;
    constexpr int FN = BN / WC / 16;
    constexpr int ACH = BM * 8;   // 16B chunks per A K-tile
    constexpr int BCH = BN * 8;
    __shared__ __align__(16) short As[2][BM * 64];
    __shared__ __align__(16) short Bs[2][BN * 64];
    const int tid = threadIdx.x;
    const int z = blockIdx.z;
    A  += (long)z * sA;
    Bt += (long)z * sB;
    const int bm = (SWAP ? blockIdx.x : blockIdx.y) * BM;
    const int bn = (SWAP ? blockIdx.y : blockIdx.x) * BN;
    const int w = tid >> 6, lane = tid & 63;
    const int wr = w / WC, wc = w % WC;
    const int moff = wr * (BM / WR), noff = wc * (BN / WC);
    floatx4 acc[FM][FN] = {};

    auto stage = [&](int buf, int k0) {
        #pragma unroll
        for (int i = 0; i < ACH / 256; i++) {
            int c = tid + i * 256;
            int m = c >> 3, u = (c & 7) ^ (m & 7);     // pre-swizzled source
            const __hip_bfloat16* src = A + (long)(bm + m) * lda + k0 + u * 8;
            char* dst = (char*)&As[buf][0] + (w * 64 + i * 256) * 16;
            GLOAD16(src, dst);
        }
        #pragma unroll
        for (int i = 0; i < BCH / 256; i++) {
            int c = tid + i * 256;
            int m = c >> 3, u = (c & 7) ^ (m & 7);
            const __hip_bfloat16* src = Bt + (long)(bn + m) * ldb + k0 + u * 8;
            char* dst = (char*)&Bs[buf][0] + (w * 64 + i * 256) * 16;
            GLOAD16(src, dst);
        }
    };

    const int nt = Kdim >> 6;
    stage(0, 0);
    __syncthreads();
    int cur = 0;
    for (int t = 0; t < nt; ++t) {
        if (t + 1 < nt) stage(cur ^ 1, (t + 1) * 64);   // prefetch flies under MFMA
        #pragma unroll
        for (int kk = 0; kk < 2; kk++) {
            bhalf8 af[FM], bf[FN];
            #pragma unroll
            for (int fm = 0; fm < FM; fm++) {
                int row = moff + fm * 16 + (lane & 15);
                int u = (kk * 4 + (lane >> 4)) ^ (row & 7);
                af[fm] = *(const bhalf8*)((const char*)&As[cur][0] + row * 128 + u * 16);
            }
            #pragma unroll
            for (int fn = 0; fn < FN; fn++) {
                int row = noff + fn * 16 + (lane & 15);
                int u = (kk * 4 + (lane >> 4)) ^ (row & 7);
                bf[fn] = *(const bhalf8*)((const char*)&Bs[cur][0] + row * 128 + u * 16);
            }
            #pragma unroll
            for (int fm = 0; fm < FM; fm++)
                #pragma unroll
                for (int fn = 0; fn < FN; fn++)
                    acc[fm][fn] = __builtin_amdgcn_mfma_f32_16x16x32_bf16(
                        af[fm], bf[fn], acc[fm][fn], 0, 0, 0);
        }
        __syncthreads();   // drains vmcnt: next tile landed during compute
        cur ^= 1;
    }

    float* Cf = (float*)Cv;
    __hip_bfloat16* Cb = (__hip_bfloat16*)Cv;
    const long zoff = (long)z * sC;
    const int lr = lane >> 4, lc = lane & 15;
    float alphaV = (EPI == 3) ? bias[0] : 0.f;
    #pragma unroll
    for (int fm = 0; fm < FM; fm++) {
        #pragma unroll
        for (int fn = 0; fn < FN; fn++) {
            int cN = bn + noff + fn * 16 + lc;
            float bv = (EPI == 3 || !bias) ? 0.f : bias[cN];
            #pragma unroll
            for (int i = 0; i < 4; i++) {
                int rM = bm + moff + fm * 16 + lr * 4 + i;
                long idx = zoff + (long)rM * ldc + cN;
                float v = acc[fm][fn][i] + bv;
                if constexpr (EPI == 0) Cf[idx] = v;
                else if constexpr (EPI == 1) Cb[idx] = __float2bfloat16(v);
                else if constexpr (EPI == 2) Cb[idx] = __float2bfloat16(gelu_f(v));
                else if constexpr (EPI == 3)
                    Cb[idx] = __float2bfloat16(aux[idx] + alphaV * acc[fm][fn][i]);
                else if constexpr (EPI == 4) Cf[idx] += v;
            }
        }
    }
}

// ------------------------------------------------------------- flash attention
__global__ __launch_bounds__(256) void attn_mfma(
    const __hip_bfloat16* __restrict__ qkv,
    const __hip_bfloat16* __restrict__ vt,
    __hip_bfloat16* __restrict__ catB)
{
    __shared__ short pbuf[4][16][72];
    const int tid = threadIdx.x;
    const int w = tid >> 6, lane = tid & 63;
    const int g = lane >> 4, ql = lane & 15;
    const int h = blockIdx.y, b = blockIdx.z;
    const int qbase = blockIdx.x * 64 + w * 16;

    const long qrow = ((long)(b * S_ + qbase + ql)) * 1536 + h * DH_;
    bhalf8 qa0 = *(const bhalf8*)(qkv + qrow + g * 8);
    bhalf8 qa1 = *(const bhalf8*)(qkv + qrow + 32 + g * 8);
    const __hip_bfloat16* kB = qkv + 512;
    const __hip_bfloat16* vbase = vt + ((long)(b * H_ + h)) * DH_ * S_;

    floatx4 o[4] = {};
    float m = -INFINITY, ls = 0.f;
    const float SC = 0.125f * 1.44269504088896f;
    const int nblk = blockIdx.x + 1;

    for (int kvb = 0; kvb < nblk; kvb++) {
        const int kb0 = kvb * 64;
        floatx4 st[4];
        #pragma unroll
        for (int t = 0; t < 4; t++) {
            long krow = ((long)(b * S_ + kb0 + t * 16 + ql)) * 1536 + h * DH_;
            bhalf8 ka0 = *(const bhalf8*)(kB + krow + g * 8);
            bhalf8 ka1 = *(const bhalf8*)(kB + krow + 32 + g * 8);
            floatx4 z = {};
            z = __builtin_amdgcn_mfma_f32_16x16x32_bf16(ka0, qa0, z, 0, 0, 0);
            z = __builtin_amdgcn_mfma_f32_16x16x32_bf16(ka1, qa1, z, 0, 0, 0);
            st[t] = z;
        }
        const int q = qbase + ql;
        float p[4][4];
        float m4 = -INFINITY;
        #pragma unroll
        for (int t = 0; t < 4; t++)
            #pragma unroll
            for (int i = 0; i < 4; i++) {
                int kv = kb0 + t * 16 + g * 4 + i;
                float v = (kv <= q) ? st[t][i] * SC : -INFINITY;
                p[t][i] = v; m4 = fmaxf(m4, v);
            }
        m4 = fmaxf(m4, __shfl_xor(m4, 16));
        m4 = fmaxf(m4, __shfl_xor(m4, 32));
        float mnew = fmaxf(m, m4);
        float corr = exp2f(m - mnew);
        m = mnew;
        float lsum = 0.f;
        #pragma unroll
        for (int t = 0; t < 4; t++)
            #pragma unroll
            for (int i = 0; i < 4; i++) {
                float e = exp2f(p[t][i] - mnew);
                p[t][i] = e; lsum += e;
            }
        lsum += __shfl_xor(lsum, 16);
        lsum += __shfl_xor(lsum, 32);
        ls = ls * corr + lsum;
        unsigned* prow = (unsigned*)&pbuf[w][ql][0];
        #pragma unroll
        for (int t = 0; t < 4; t++) {
            prow[t * 8 + g * 2]     = pk2(p[t][0], p[t][1]);
            prow[t * 8 + g * 2 + 1] = pk2(p[t][2], p[t][3]);
        }
        #pragma unroll
        for (int i = 0; i < 4; i++) {
            float c = __shfl(corr, g * 4 + i);
            #pragma unroll
            for (int dt = 0; dt < 4; dt++) o[dt][i] *= c;
        }
        __syncthreads();
        #pragma unroll
        for (int ks = 0; ks < 2; ks++) {
            bhalf8 pa = *(const bhalf8*)&pbuf[w][ql][ks * 32 + g * 8];
            #pragma unroll
            for (int dt = 0; dt < 4; dt++) {
                bhalf8 vb = *(const bhalf8*)(vbase + (long)(dt * 16 + ql) * S_ + kb0 + ks * 32 + g * 8);
                o[dt] = __builtin_amdgcn_mfma_f32_16x16x32_bf16(pa, vb, o[dt], 0, 0, 0);
            }
        }
        __syncthreads();
    }
    const float inv = 1.f / ls;
    #pragma unroll
    for (int i = 0; i < 4; i++) {
        float iv = __shfl(inv, g * 4 + i);
        int trow = b * S_ + qbase + g * 4 + i;
        #pragma unroll
        for (int dt = 0; dt < 4; dt++)
            catB[(long)trow * 1024 + 512 + h * DH_ + dt * 16 + ql] =
                __float2bfloat16(o[dt][i] * iv);
    }
}

__global__ __launch_bounds__(256) void vtrans(const __hip_bfloat16* __restrict__ qkv,
                                              __hip_bfloat16* __restrict__ vt) {
    __shared__ short tl[32][33];
    int bh = blockIdx.z; int b = bh >> 3, h = bh & 7;
    int s0 = blockIdx.x * 32, d0 = blockIdx.y * 32;
    int tx = threadIdx.x & 31, ty = threadIdx.x >> 5;
    #pragma unroll
    for (int r = 0; r < 4; r++)
        tl[ty * 4 + r][tx] = *(const short*)(qkv + (long)(b * S_ + s0 + ty * 4 + r) * 1536
                                             + 1024 + h * DH_ + d0 + tx);
    __syncthreads();
    #pragma unroll
    for (int r = 0; r < 4; r++)
        *(short*)(vt + (long)bh * DH_ * S_ + (long)(d0 + ty * 4 + r) * S_ + s0 + tx)
            = tl[tx][ty * 4 + r];
}

// ------------------------------------------------------------- conversions
__global__ __launch_bounds__(256) void tcvt(const float* __restrict__ in, int ldn, long sIn,
                                            __hip_bfloat16* __restrict__ out, int ldk, long sOut) {
    __shared__ float t[32][33];
    in  += (long)blockIdx.z * sIn;
    out += (long)blockIdx.z * sOut;
    int k0 = blockIdx.y * 32, n0 = blockIdx.x * 32;
    int tx = threadIdx.x & 31, ty = threadIdx.x >> 5;
    #pragma unroll
    for (int r = 0; r < 4; r++) t[ty * 4 + r][tx] = in[(long)(k0 + ty * 4 + r) * ldn + n0 + tx];
    __syncthreads();
    #pragma unroll
    for (int r = 0; r < 4; r++)
        out[(long)(n0 + ty * 4 + r) * ldk + k0 + tx] = __float2bfloat16(t[tx][ty * 4 + r]);
}

__global__ void cvt_temb(const float* __restrict__ in, __hip_bfloat16* __restrict__ out) {
    long i = ((long)blockIdx.x * 256 + threadIdx.x) * 4;
    float4 v = *(const float4*)(in + i);
    out[i]     = __float2bfloat16(v.x);
    out[i + 1] = __float2bfloat16(v.y);
    out[i + 2] = __float2bfloat16(v.z);
    out[i + 3] = __float2bfloat16(v.w);
}

__global__ void basis_prep(const float* __restrict__ A,
                           __hip_bfloat16* __restrict__ projT,
                           __hip_bfloat16* __restrict__ deltaT) {
    long i = (long)blockIdx.x * 256 + threadIdx.x;
    if (i >= (long)NB_ * D_ * R_) return;
    int r = i & 63; int d = (i >> 6) & 511; int n = i >> 15;
    __hip_bfloat16 v = __float2bfloat16(A[i]);
    projT[((long)n * R_ + r) * D_ + d] = v;
    deltaT[(long)d * (NB_ * R_) + n * R_ + r] = v;
}

__global__ void bias_cat(const float* __restrict__ bq, const float* __restrict__ bk,
                         const float* __restrict__ bv, float* __restrict__ o) {
    int i = blockIdx.x * 256 + threadIdx.x;
    int l = i / 1536, j = i % 1536;
    float v = (j < 512) ? bq[l * 512 + j] : (j < 1024) ? bk[l * 512 + j - 512]
                                                       : bv[l * 512 + j - 1024];
    o[i] = v;
}

// ------------------------------------------------------------- helpers
__global__ void embed_kernel(const int* __restrict__ ids, const float* __restrict__ temb,
                             const float* __restrict__ pemb, float* __restrict__ x) {
    int t = blockIdx.x;
    int s = t % S_;
    int id = ids[t];
    for (int d = threadIdx.x; d < D_; d += blockDim.x)
        x[(long)t * D_ + d] = temb[(long)id * D_ + d] + pemb[(long)s * D_ + d];
}

__global__ __launch_bounds__(256) void ln_kernel(const float* __restrict__ in,
                                                 const float* __restrict__ g,
                                                 const float* __restrict__ b,
                                                 float* __restrict__ outf,
                                                 __hip_bfloat16* __restrict__ outb, int ldo) {
    int t = blockIdx.x;
    const float* row = in + (long)t * D_;
    int tid = threadIdx.x;
    float v0 = row[tid], v1 = row[tid + 256];
    __shared__ float red[256];
    red[tid] = v0 + v1; __syncthreads();
    for (int off = 128; off; off >>= 1) { if (tid < off) red[tid] += red[tid + off]; __syncthreads(); }
    float mean = red[0] * (1.0f / D_); __syncthreads();
    float d0 = v0 - mean, d1 = v1 - mean;
    red[tid] = d0 * d0 + d1 * d1; __syncthreads();
    for (int off = 128; off; off >>= 1) { if (tid < off) red[tid] += red[tid + off]; __syncthreads(); }
    float rstd = rsqrtf(red[0] * (1.0f / D_) + 1e-5f);
    float o0 = d0 * rstd * g[tid]       + b[tid];
    float o1 = d1 * rstd * g[tid + 256] + b[tid + 256];
    if (outf) {
        outf[(long)t * D_ + tid]       = o0;
        outf[(long)t * D_ + tid + 256] = o1;
    }
    outb[(long)t * ldo + tid]       = __float2bfloat16(o0);
    outb[(long)t * ldo + tid + 256] = __float2bfloat16(o1);
}

__global__ void ne_kernel(const float* __restrict__ rec, const float* __restrict__ bemb,
                          __hip_bfloat16* __restrict__ neb, float* __restrict__ sel) {
    int n = blockIdx.x;
    __shared__ float w[NB_];
    if (threadIdx.x == 0) {
        float mx = -1e30f;
        for (int i = 0; i < NB_; i++) mx = fmaxf(mx, rec[n * NB_ + i]);
        float sm = 0.f;
        for (int i = 0; i < NB_; i++) { float e = expf(rec[n * NB_ + i] - mx); w[i] = e; sm += e; }
        float inv = 1.f / sm;
        for (int i = 0; i < NB_; i++) w[i] *= inv;
    }
    __syncthreads();
    if (threadIdx.x < NB_) sel[n * NB_ + threadIdx.x] = w[threadIdx.x];
    for (int d = threadIdx.x; d < D_; d += blockDim.x) {
        float acc = 0.f;
        #pragma unroll
        for (int nb = 0; nb < NB_; nb++) acc += w[nb] * bemb[nb * D_ + d];
        neb[(long)n * D_ + d] = __float2bfloat16(acc);
    }
}

__global__ __launch_bounds__(64) void route_kernel(const float* __restrict__ scores,
                                                   const float* __restrict__ sel,
                                                   float* __restrict__ tr) {
    int t = blockIdx.x, lane = threadIdx.x;
    float myval = scores[(long)t * N_ + lane];
    float topv[K_]; int topi[K_];
    #pragma unroll
    for (int kk = 0; kk < K_; kk++) {
        float v = myval; int idx = lane;
        #pragma unroll
        for (int off = 32; off; off >>= 1) {
            float ov = __shfl_down(v, off);
            int oi = __shfl_down(idx, off);
            if (ov > v || (ov == v && oi < idx)) { v = ov; idx = oi; }
        }
        v = __shfl(v, 0); idx = __shfl(idx, 0);
        topv[kk] = v; topi[kk] = idx;
        if (lane == idx) myval = -INFINITY;
    }
    float mx = topv[0];
    float w[K_], sum = 0.f;
    #pragma unroll
    for (int kk = 0; kk < K_; kk++) { w[kk] = expf(topv[kk] - mx); sum += w[kk]; }
    float inv = 1.f / sum;
    if (lane < NB_) {
        float acc = 0.f;
        #pragma unroll
        for (int kk = 0; kk < K_; kk++) acc += w[kk] * inv * sel[topi[kk] * NB_ + lane];
        tr[(long)t * NB_ + lane] = acc;
    }
}

// h[r] = sum_n tr[n]*proj[t][n*64+r]; g[t][n*64+r] = bf16(tr[n]*h[r])
__global__ __launch_bounds__(256) void hg_kernel(const float* __restrict__ tr,
                                                 const float* __restrict__ P,
                                                 __hip_bfloat16* __restrict__ g) {
    int t = blockIdx.x, tid = threadIdx.x;
    __shared__ float hl[64];
    __shared__ float trl[32];
    if (tid < 32) trl[tid] = tr[(long)t * 32 + tid];
    __syncthreads();
    if (tid < 64) {
        float acc = 0.f;
        const float* p = P + (long)t * 2048 + tid;
        #pragma unroll
        for (int n = 0; n < 32; n++) acc += trl[n] * p[n * 64];
        hl[tid] = acc;
    }
    __syncthreads();
    #pragma unroll
    for (int j = 0; j < 8; j++) {
        int idx = tid * 8 + j;
        int n = idx >> 6, r = idx & 63;
        g[(long)t * 2048 + idx] = __float2bfloat16(trl[n] * hl[r]);
    }
}

// ------------------------------------------------------------- launch
extern "C" void kernel_launch(void* const* d_in, const int* in_sizes, int n_in,
                              void* d_out, int out_size, void* d_ws, size_t ws_size,
                              hipStream_t stream) {
    const int*   ids    = (const int*)d_in[0];
    const float* temb   = (const float*)d_in[1];
    const float* pemb   = (const float*)d_in[2];
    const float* basisA = (const float*)d_in[3];
    const float* bemb   = (const float*)d_in[4];
    const float* recipe = (const float*)d_in[5];
    const float* Wq = (const float*)d_in[6],  *bq = (const float*)d_in[7];
    const float* Wk = (const float*)d_in[8],  *bk = (const float*)d_in[9];
    const float* Wv = (const float*)d_in[10], *bv = (const float*)d_in[11];
    const float* Ws = (const float*)d_in[12], *bs = (const float*)d_in[13];
    const float* Wup = (const float*)d_in[14], *bup = (const float*)d_in[15];
    const float* Wdn = (const float*)d_in[16], *bdn = (const float*)d_in[17];
    const float* ln1g = (const float*)d_in[18], *ln1b = (const float*)d_in[19];
    const float* ln2g = (const float*)d_in[20], *ln2b = (const float*)d_in[21];
    const float* alpha = (const float*)d_in[22];
    const float* lnfg = (const float*)d_in[23], *lnfb = (const float*)d_in[24];
    float* out = (float*)d_out;
    float* W = (float*)d_ws;

    // fp32 arena (float offsets)
    float* x    = W + 0;          // 524288
    float* buf1 = W + 524288;     // n2 f32 (xf input)
    float* scb  = W + 1048576;    // scores 65536
    float* trb  = W + 1114112;    // 32768
    float* sel  = W + 1212416;    // 2048
    float* P    = W + 1214464;    // proj f32 2097152
    float* bqkv = W + 3835904;    // 6144
    // bf16 arena
    __hip_bfloat16* SB = (__hip_bfloat16*)(W + 3844096);
    __hip_bfloat16* tembB  = SB + 0;          // 16384000
    __hip_bfloat16* qkvT   = SB + 16384000;   // 3145728
    __hip_bfloat16* WsT    = SB + 19529728;   // 2097152
    __hip_bfloat16* WupT   = SB + 21626880;   // 4194304
    __hip_bfloat16* WdnT   = SB + 25821184;   // 4194304
    __hip_bfloat16* projT  = SB + 30015488;   // 1048576
    __hip_bfloat16* deltaT = SB + 31064064;   // 1048576
    __hip_bfloat16* neB    = SB + 32112640;   // 32768
    __hip_bfloat16* catB   = SB + 32145408;   // 1048576
    __hip_bfloat16* qryB   = SB + 33193984;   // 524288
    __hip_bfloat16* n2B    = SB + 33718272;   // 524288
    __hip_bfloat16* xfB    = SB + 34242560;   // 524288
    __hip_bfloat16* gB     = SB + 34766848;   // 2097152
    __hip_bfloat16* ffhB   = SB + 36864000;   // 2097152
    __hip_bfloat16* qkvB   = SB + 38961152;   // 1572864
    __hip_bfloat16* VtB    = SB + 40534016;   // 524288

    dim3 blk(256);
    // ---- one-time conversions ----
    cvt_temb<<<16000, blk, 0, stream>>>(temb, tembB);
    basis_prep<<<4096, blk, 0, stream>>>(basisA, projT, deltaT);
    bias_cat<<<24, blk, 0, stream>>>(bq, bk, bv, bqkv);
    tcvt<<<dim3(16, 16, 4), blk, 0, stream>>>(Wq, D_, (long)D_ * D_, qkvT, D_, (long)1536 * D_);
    tcvt<<<dim3(16, 16, 4), blk, 0, stream>>>(Wk, D_, (long)D_ * D_, qkvT + 512 * 512, D_, (long)1536 * D_);
    tcvt<<<dim3(16, 16, 4), blk, 0, stream>>>(Wv, D_, (long)D_ * D_, qkvT + 1024 * 512, D_, (long)1536 * D_);
    tcvt<<<dim3(16, 32, 4), blk, 0, stream>>>(Ws, D_, (long)2 * D_ * D_, WsT, 2 * D_, (long)2 * D_ * D_);
    tcvt<<<dim3(64, 16, 4), blk, 0, stream>>>(Wup, DFF_, (long)D_ * DFF_, WupT, D_, (long)D_ * DFF_);
    tcvt<<<dim3(16, 64, 4), blk, 0, stream>>>(Wdn, D_, (long)DFF_ * D_, WdnT, DFF_, (long)DFF_ * D_);
    embed_kernel<<<T_, blk, 0, stream>>>(ids, temb, pemb, x);

    for (int l = 0; l < L_; l++) {
        ne_kernel<<<N_, blk, 0, stream>>>(recipe + (long)l * N_ * NB_, bemb, neB, sel);
        ln_kernel<<<T_, blk, 0, stream>>>(x, ln1g + l * D_, ln1b + l * D_, nullptr, catB, 1024);
        // fused QKV: [1024,1536] bf16
        gemm_mfma<64, 64, 2, 2, 1><<<dim3(24, 16), blk, 0, stream>>>(
            catB, 1024, 0, qkvT + (long)l * 1536 * 512, D_, 0, bqkv + l * 1536, nullptr,
            qkvB, 1536, 0, D_);
        vtrans<<<dim3(16, 2, 16), blk, 0, stream>>>(qkvB, VtB);
        attn_mfma<<<dim3(8, H_, B_), blk, 0, stream>>>(qkvB, VtB, catB);
        // query = cat @ Ws + bs -> bf16
        gemm_mfma<64, 64, 2, 2, 1><<<dim3(8, 16), blk, 0, stream>>>(
            catB, 2 * D_, 0, WsT + (long)l * 2 * D_ * D_, 2 * D_, 0, bs + l * D_, nullptr,
            qryB, D_, 0, 2 * D_);
        // scores = query @ ne^T (f32 out), then parallel top-k route
        gemm_mfma<128, 64, 2, 2, 0><<<dim3(1, 8), blk, 0, stream>>>(
            qryB, D_, 0, neB, D_, 0, nullptr, nullptr, scb, N_, 0, D_);
        route_kernel<<<T_, dim3(64), 0, stream>>>(scb, sel, trb);
        ln_kernel<<<T_, blk, 0, stream>>>(x, ln2g + l * D_, ln2b + l * D_, buf1, n2B, 512);
        // proj: batched over n (z=32)
        gemm_mfma<128, 64, 2, 2, 0><<<dim3(1, 8, NB_), blk, 0, stream>>>(
            n2B, D_, 0, projT, D_, (long)R_ * D_, nullptr, nullptr, P, NB_ * R_, R_, D_);
        hg_kernel<<<T_, blk, 0, stream>>>(trb, P, gB);
        // delta GEMM + fused xf: xfB = bf16(n2 + alpha*delta)
        gemm_mfma<64, 64, 2, 2, 3><<<dim3(8, 16), blk, 0, stream>>>(
            gB, NB_ * R_, 0, deltaT, NB_ * R_, 0, alpha + l, buf1,
            xfB, D_, 0, NB_ * R_);
        // FFN up (+gelu, bf16 out)
        gemm_mfma<64, 64, 2, 2, 2><<<dim3(32, 16), blk, 0, stream>>>(
            xfB, D_, 0, WupT + (long)l * D_ * DFF_, D_, 0, bup + l * DFF_, nullptr,
            ffhB, DFF_, 0, D_);
        // FFN down fused residual: x += down + bias
        gemm_mfma<64, 64, 2, 2, 4><<<dim3(8, 16), blk, 0, stream>>>(
            ffhB, DFF_, 0, WdnT + (long)l * DFF_ * D_, DFF_, 0, bdn + l * D_, nullptr,
            x, D_, 0, DFF_);
    }
    // final LN + tied head (SWAP grid: 8 row-tiles fastest for B-panel reuse)
    ln_kernel<<<T_, blk, 0, stream>>>(x, lnfg, lnfb, nullptr, n2B, 512);
    gemm_mfma<128, 128, 2, 2, 0, true><<<dim3(8, 250), blk, 0, stream>>>(
        n2B, D_, 0, tembB, D_, 0, nullptr, nullptr, out, V_, 0, D_);
}

// Round 6
// 623.372 us; speedup vs baseline: 1.4919x; 1.0710x over previous
//
#include <hip/hip_runtime.h>
#include <hip/hip_bf16.h>
#include <math.h>

// Problem constants
#define V_  32000
#define D_  512
#define DFF_ 2048
#define L_  4
#define H_  8
#define N_  64
#define K_  8
#define NB_ 32
#define R_  64
#define B_  2
#define S_  512
#define T_  1024   // B*S
#define DH_ 64

typedef short bhalf8 __attribute__((ext_vector_type(8)));
typedef float floatx4 __attribute__((ext_vector_type(4)));

#define GLOAD16(gp, lp) __builtin_amdgcn_global_load_lds( \
    (const __attribute__((address_space(1))) void*)(gp), \
    (__attribute__((address_space(3))) void*)(lp), 16, 0, 0)

__device__ __forceinline__ float gelu_f(float v) {
    return 0.5f * v * (1.0f + erff(v * 0.70710678118654752f));
}

__device__ __forceinline__ unsigned pk2(float a, float b) {
    unsigned ua = (unsigned)__bfloat16_as_ushort(__float2bfloat16(a));
    unsigned ub = (unsigned)__bfloat16_as_ushort(__float2bfloat16(b));
    return ua | (ub << 16);
}

// ------------------------------------------------------------- MFMA GEMM
// C[M,N] = A[M,K] @ Bt[N,K]^T (+bias). A,Bt bf16 row-major. 256 threads,
// 4 waves WRxWC. BK=64, double-buffered LDS, XOR-swizzle (16B unit u^=row&7).
// EPI: 0=f32 store, 1=bf16 store, 2=bf16 gelu, 3=xf (bf16(aux + bias[0]*acc)),
//      4=f32 accumulate (C += acc + bias), 5=bf16 store + V->Vt scatter (aux=Vt).
// SWAP: blockIdx.x indexes M-tiles. SWZ=1: head mapping — 2048 linear blocks,
//       XCD-bijective so all 8 M-tiles of one 128-col B panel run on one XCD.
template<int BM, int BN, int WR, int WC, int EPI, bool SWAP = false, int SWZ = 0>
__global__ __launch_bounds__(256) void gemm_mfma(
    const __hip_bfloat16* __restrict__ A, int lda, long sA,
    const __hip_bfloat16* __restrict__ Bt, int ldb, long sB,
    const float* __restrict__ bias,
    const float* __restrict__ aux,
    void* __restrict__ Cv, int ldc, long sC,
    int Kdim)
{
    constexpr int FM = BM / WR / 16;
    constexpr int FN = BN / WC / 16;
    constexpr int ACH = BM * 8;   // 16B chunks per A K-tile
    constexpr int BCH = BN * 8;
    __shared__ __align__(16) short As[2][BM * 64];
    __shared__ __align__(16) short Bs[2][BN * 64];
    const int tid = threadIdx.x;
    const int z = blockIdx.z;
    A  += (long)z * sA;
    Bt += (long)z * sB;
    int bm, bn;
    if constexpr (SWZ == 1) {
        // head: 8 m-tiles x 250 n-panels; dispatch d -> XCD d&7 (round-robin).
        int d = blockIdx.x;
        int xcd = d & 7, k = d >> 3;          // k in [0,256)
        int ty = xcd * 32 + (k >> 3);
        if (ty >= 250) return;
        bm = (k & 7) * BM;
        bn = ty * BN;
    } else {
        bm = (SWAP ? blockIdx.x : blockIdx.y) * BM;
        bn = (SWAP ? blockIdx.y : blockIdx.x) * BN;
    }
    const int w = tid >> 6, lane = tid & 63;
    const int wr = w / WC, wc = w % WC;
    const int moff = wr * (BM / WR), noff = wc * (BN / WC);
    floatx4 acc[FM][FN] = {};

    auto stage = [&](int buf, int k0) {
        #pragma unroll
        for (int i = 0; i < ACH / 256; i++) {
            int c = tid + i * 256;
            int m = c >> 3, u = (c & 7) ^ (m & 7);     // pre-swizzled source
            const __hip_bfloat16* src = A + (long)(bm + m) * lda + k0 + u * 8;
            char* dst = (char*)&As[buf][0] + (w * 64 + i * 256) * 16;
            GLOAD16(src, dst);
        }
        #pragma unroll
        for (int i = 0; i < BCH / 256; i++) {
            int c = tid + i * 256;
            int m = c >> 3, u = (c & 7) ^ (m & 7);
            const __hip_bfloat16* src = Bt + (long)(bn + m) * ldb + k0 + u * 8;
            char* dst = (char*)&Bs[buf][0] + (w * 64 + i * 256) * 16;
            GLOAD16(src, dst);
        }
    };

    const int nt = Kdim >> 6;
    stage(0, 0);
    __syncthreads();
    int cur = 0;
    for (int t = 0; t < nt; ++t) {
        if (t + 1 < nt) stage(cur ^ 1, (t + 1) * 64);   // prefetch flies under MFMA
        #pragma unroll
        for (int kk = 0; kk < 2; kk++) {
            bhalf8 af[FM], bf[FN];
            #pragma unroll
            for (int fm = 0; fm < FM; fm++) {
                int row = moff + fm * 16 + (lane & 15);
                int u = (kk * 4 + (lane >> 4)) ^ (row & 7);
                af[fm] = *(const bhalf8*)((const char*)&As[cur][0] + row * 128 + u * 16);
            }
            #pragma unroll
            for (int fn = 0; fn < FN; fn++) {
                int row = noff + fn * 16 + (lane & 15);
                int u = (kk * 4 + (lane >> 4)) ^ (row & 7);
                bf[fn] = *(const bhalf8*)((const char*)&Bs[cur][0] + row * 128 + u * 16);
            }
            #pragma unroll
            for (int fm = 0; fm < FM; fm++)
                #pragma unroll
                for (int fn = 0; fn < FN; fn++)
                    acc[fm][fn] = __builtin_amdgcn_mfma_f32_16x16x32_bf16(
                        af[fm], bf[fn], acc[fm][fn], 0, 0, 0);
        }
        __syncthreads();   // drains vmcnt: next tile landed during compute
        cur ^= 1;
    }

    float* Cf = (float*)Cv;
    __hip_bfloat16* Cb = (__hip_bfloat16*)Cv;
    __hip_bfloat16* vtb = (EPI == 5) ? (__hip_bfloat16*)(void*)aux : nullptr;
    const long zoff = (long)z * sC;
    const int lr = lane >> 4, lc = lane & 15;
    float alphaV = (EPI == 3) ? bias[0] : 0.f;
    #pragma unroll
    for (int fm = 0; fm < FM; fm++) {
        #pragma unroll
        for (int fn = 0; fn < FN; fn++) {
            int cN = bn + noff + fn * 16 + lc;
            float bv = (EPI == 3 || !bias) ? 0.f : bias[cN];
            #pragma unroll
            for (int i = 0; i < 4; i++) {
                int rM = bm + moff + fm * 16 + lr * 4 + i;
                long idx = zoff + (long)rM * ldc + cN;
                float v = acc[fm][fn][i] + bv;
                if constexpr (EPI == 0) Cf[idx] = v;
                else if constexpr (EPI == 1) Cb[idx] = __float2bfloat16(v);
                else if constexpr (EPI == 2) Cb[idx] = __float2bfloat16(gelu_f(v));
                else if constexpr (EPI == 3)
                    Cb[idx] = __float2bfloat16(aux[idx] + alphaV * acc[fm][fn][i]);
                else if constexpr (EPI == 4) Cf[idx] += v;
                else if constexpr (EPI == 5) {
                    __hip_bfloat16 bvv = __float2bfloat16(v);
                    Cb[idx] = bvv;
                    if (cN >= 1024) {   // V columns -> Vt[(b*8+h)][dh][s]
                        int hh = (cN - 1024) >> 6, dh = (cN - 1024) & 63;
                        int bb = rM >> 9, ss = rM & 511;
                        vtb[(((long)bb * 8 + hh) * 64 + dh) * 512 + ss] = bvv;
                    }
                }
            }
        }
    }
}

// ------------------------------------------------------------- flash attention
__global__ __launch_bounds__(256) void attn_mfma(
    const __hip_bfloat16* __restrict__ qkv,
    const __hip_bfloat16* __restrict__ vt,
    __hip_bfloat16* __restrict__ catB)
{
    __shared__ short pbuf[4][16][72];
    const int tid = threadIdx.x;
    const int w = tid >> 6, lane = tid & 63;
    const int g = lane >> 4, ql = lane & 15;
    const int h = blockIdx.y, b = blockIdx.z;
    const int qbase = blockIdx.x * 64 + w * 16;

    const long qrow = ((long)(b * S_ + qbase + ql)) * 1536 + h * DH_;
    bhalf8 qa0 = *(const bhalf8*)(qkv + qrow + g * 8);
    bhalf8 qa1 = *(const bhalf8*)(qkv + qrow + 32 + g * 8);
    const __hip_bfloat16* kB = qkv + 512;
    const __hip_bfloat16* vbase = vt + ((long)(b * H_ + h)) * DH_ * S_;

    floatx4 o[4] = {};
    float m = -INFINITY, ls = 0.f;
    const float SC = 0.125f * 1.44269504088896f;
    const int nblk = blockIdx.x + 1;

    for (int kvb = 0; kvb < nblk; kvb++) {
        const int kb0 = kvb * 64;
        floatx4 st[4];
        #pragma unroll
        for (int t = 0; t < 4; t++) {
            long krow = ((long)(b * S_ + kb0 + t * 16 + ql)) * 1536 + h * DH_;
            bhalf8 ka0 = *(const bhalf8*)(kB + krow + g * 8);
            bhalf8 ka1 = *(const bhalf8*)(kB + krow + 32 + g * 8);
            floatx4 z = {};
            z = __builtin_amdgcn_mfma_f32_16x16x32_bf16(ka0, qa0, z, 0, 0, 0);
            z = __builtin_amdgcn_mfma_f32_16x16x32_bf16(ka1, qa1, z, 0, 0, 0);
            st[t] = z;
        }
        const int q = qbase + ql;
        float p[4][4];
        float m4 = -INFINITY;
        #pragma unroll
        for (int t = 0; t < 4; t++)
            #pragma unroll
            for (int i = 0; i < 4; i++) {
                int kv = kb0 + t * 16 + g * 4 + i;
                float v = (kv <= q) ? st[t][i] * SC : -INFINITY;
                p[t][i] = v; m4 = fmaxf(m4, v);
            }
        m4 = fmaxf(m4, __shfl_xor(m4, 16));
        m4 = fmaxf(m4, __shfl_xor(m4, 32));
        float mnew = fmaxf(m, m4);
        float corr = exp2f(m - mnew);
        m = mnew;
        float lsum = 0.f;
        #pragma unroll
        for (int t = 0; t < 4; t++)
            #pragma unroll
            for (int i = 0; i < 4; i++) {
                float e = exp2f(p[t][i] - mnew);
                p[t][i] = e; lsum += e;
            }
        lsum += __shfl_xor(lsum, 16);
        lsum += __shfl_xor(lsum, 32);
        ls = ls * corr + lsum;
        unsigned* prow = (unsigned*)&pbuf[w][ql][0];
        #pragma unroll
        for (int t = 0; t < 4; t++) {
            prow[t * 8 + g * 2]     = pk2(p[t][0], p[t][1]);
            prow[t * 8 + g * 2 + 1] = pk2(p[t][2], p[t][3]);
        }
        #pragma unroll
        for (int i = 0; i < 4; i++) {
            float c = __shfl(corr, g * 4 + i);
            #pragma unroll
            for (int dt = 0; dt < 4; dt++) o[dt][i] *= c;
        }
        __syncthreads();
        #pragma unroll
        for (int ks = 0; ks < 2; ks++) {
            bhalf8 pa = *(const bhalf8*)&pbuf[w][ql][ks * 32 + g * 8];
            #pragma unroll
            for (int dt = 0; dt < 4; dt++) {
                bhalf8 vb = *(const bhalf8*)(vbase + (long)(dt * 16 + ql) * S_ + kb0 + ks * 32 + g * 8);
                o[dt] = __builtin_amdgcn_mfma_f32_16x16x32_bf16(pa, vb, o[dt], 0, 0, 0);
            }
        }
        __syncthreads();
    }
    const float inv = 1.f / ls;
    #pragma unroll
    for (int i = 0; i < 4; i++) {
        float iv = __shfl(inv, g * 4 + i);
        int trow = b * S_ + qbase + g * 4 + i;
        #pragma unroll
        for (int dt = 0; dt < 4; dt++)
            catB[(long)trow * 1024 + 512 + h * DH_ + dt * 16 + ql] =
                __float2bfloat16(o[dt][i] * iv);
    }
}

// ------------------------------------------------------------- merged prologue
__device__ __forceinline__ void tcvt_dev(const float* in, int ldn, long sIn,
                                         __hip_bfloat16* out, int ldk, long sOut,
                                         int bx, int by, int bz, float (*tsh)[33]) {
    in  += (long)bz * sIn;
    out += (long)bz * sOut;
    int k0 = by * 32, n0 = bx * 32;
    int tx = threadIdx.x & 31, ty = threadIdx.x >> 5;
    #pragma unroll
    for (int r = 0; r < 4; r++) tsh[ty * 4 + r][tx] = in[(long)(k0 + ty * 4 + r) * ldn + n0 + tx];
    __syncthreads();
    #pragma unroll
    for (int r = 0; r < 4; r++)
        out[(long)(n0 + ty * 4 + r) * ldk + k0 + tx] = __float2bfloat16(tsh[tx][ty * 4 + r]);
}

__global__ __launch_bounds__(256) void prologue_kernel(
    const float* __restrict__ temb, __hip_bfloat16* __restrict__ tembB,
    const float* __restrict__ basisA, __hip_bfloat16* __restrict__ projT,
    __hip_bfloat16* __restrict__ deltaT,
    const float* __restrict__ bq, const float* __restrict__ bk,
    const float* __restrict__ bv, float* __restrict__ bqkv,
    const float* __restrict__ Wq, const float* __restrict__ Wk,
    const float* __restrict__ Wv, __hip_bfloat16* __restrict__ qkvT,
    const float* __restrict__ Ws, __hip_bfloat16* __restrict__ WsT,
    const float* __restrict__ Wup, __hip_bfloat16* __restrict__ WupT,
    const float* __restrict__ Wdn, __hip_bfloat16* __restrict__ WdnT,
    const int* __restrict__ ids, const float* __restrict__ pemb,
    float* __restrict__ x)
{
    __shared__ float tsh[32][33];
    const int blk = blockIdx.x, tid = threadIdx.x;
    if (blk < 16000) {                       // temb f32 -> bf16
        long i = ((long)blk * 256 + tid) * 4;
        float4 v = *(const float4*)(temb + i);
        tembB[i]     = __float2bfloat16(v.x);
        tembB[i + 1] = __float2bfloat16(v.y);
        tembB[i + 2] = __float2bfloat16(v.z);
        tembB[i + 3] = __float2bfloat16(v.w);
    } else if (blk < 20096) {                // basis_A -> projT + deltaT
        long i = (long)(blk - 16000) * 256 + tid;
        int r = i & 63; int d = (i >> 6) & 511; int n = i >> 15;
        __hip_bfloat16 v = __float2bfloat16(basisA[i]);
        projT[((long)n * R_ + r) * D_ + d] = v;
        deltaT[(long)d * (NB_ * R_) + n * R_ + r] = v;
    } else if (blk < 20120) {                // bias concat
        int i = (blk - 20096) * 256 + tid;
        int l = i / 1536, j = i % 1536;
        float v = (j < 512) ? bq[l * 512 + j] : (j < 1024) ? bk[l * 512 + j - 512]
                                                           : bv[l * 512 + j - 1024];
        bqkv[i] = v;
    } else if (blk < 21144) {                // Wq
        int lin = blk - 20120;
        tcvt_dev(Wq, D_, (long)D_ * D_, qkvT, D_, (long)1536 * D_,
                 lin & 15, (lin >> 4) & 15, lin >> 8, tsh);
    } else if (blk < 22168) {                // Wk
        int lin = blk - 21144;
        tcvt_dev(Wk, D_, (long)D_ * D_, qkvT + 512 * 512, D_, (long)1536 * D_,
                 lin & 15, (lin >> 4) & 15, lin >> 8, tsh);
    } else if (blk < 23192) {                // Wv
        int lin = blk - 22168;
        tcvt_dev(Wv, D_, (long)D_ * D_, qkvT + 1024 * 512, D_, (long)1536 * D_,
                 lin & 15, (lin >> 4) & 15, lin >> 8, tsh);
    } else if (blk < 25240) {                // Ws (16,32,4)
        int lin = blk - 23192;
        tcvt_dev(Ws, D_, (long)2 * D_ * D_, WsT, 2 * D_, (long)2 * D_ * D_,
                 lin & 15, (lin >> 4) & 31, lin >> 9, tsh);
    } else if (blk < 29336) {                // Wup (64,16,4)
        int lin = blk - 25240;
        tcvt_dev(Wup, DFF_, (long)D_ * DFF_, WupT, D_, (long)D_ * DFF_,
                 lin & 63, (lin >> 6) & 15, lin >> 10, tsh);
    } else if (blk < 33432) {                // Wdn (16,64,4)
        int lin = blk - 29336;
        tcvt_dev(Wdn, D_, (long)DFF_ * D_, WdnT, DFF_, (long)DFF_ * D_,
                 lin & 15, (lin >> 4) & 63, lin >> 10, tsh);
    } else {                                 // embed
        int t = blk - 33432;
        int s = t % S_;
        int id = ids[t];
        for (int d = tid; d < D_; d += 256)
            x[(long)t * D_ + d] = temb[(long)id * D_ + d] + pemb[(long)s * D_ + d];
    }
}

// ------------------------------------------------------------- per-layer prep
// blocks 0-1023: ln1 -> catB(ld1024); 1024-2047: ln2 -> buf1 + n2B(ld512);
// 2048-2111: ne -> neB + sel.
__device__ __forceinline__ void ln_dev(const float* row, const float* g, const float* b,
                                       float* outf, __hip_bfloat16* outb, int ldo,
                                       long t, float* red) {
    int tid = threadIdx.x;
    float v0 = row[tid], v1 = row[tid + 256];
    red[tid] = v0 + v1; __syncthreads();
    for (int off = 128; off; off >>= 1) { if (tid < off) red[tid] += red[tid + off]; __syncthreads(); }
    float mean = red[0] * (1.0f / D_); __syncthreads();
    float d0 = v0 - mean, d1 = v1 - mean;
    red[tid] = d0 * d0 + d1 * d1; __syncthreads();
    for (int off = 128; off; off >>= 1) { if (tid < off) red[tid] += red[tid + off]; __syncthreads(); }
    float rstd = rsqrtf(red[0] * (1.0f / D_) + 1e-5f);
    float o0 = d0 * rstd * g[tid]       + b[tid];
    float o1 = d1 * rstd * g[tid + 256] + b[tid + 256];
    if (outf) {
        outf[t * D_ + tid]       = o0;
        outf[t * D_ + tid + 256] = o1;
    }
    outb[t * ldo + tid]       = __float2bfloat16(o0);
    outb[t * ldo + tid + 256] = __float2bfloat16(o1);
}

__global__ __launch_bounds__(256) void prep_kernel(
    const float* __restrict__ x,
    const float* __restrict__ ln1g, const float* __restrict__ ln1b,
    const float* __restrict__ ln2g, const float* __restrict__ ln2b,
    const float* __restrict__ rec, const float* __restrict__ bemb,
    __hip_bfloat16* __restrict__ catB, float* __restrict__ buf1,
    __hip_bfloat16* __restrict__ n2B,
    __hip_bfloat16* __restrict__ neb, float* __restrict__ sel)
{
    __shared__ float red[256];
    int blk = blockIdx.x;
    if (blk < 1024) {
        ln_dev(x + (long)blk * D_, ln1g, ln1b, nullptr, catB, 1024, blk, red);
    } else if (blk < 2048) {
        long t = blk - 1024;
        ln_dev(x + t * D_, ln2g, ln2b, buf1, n2B, 512, t, red);
    } else {
        int n = blk - 2048;
        __shared__ float wsm[NB_];
        if (threadIdx.x == 0) {
            float mx = -1e30f;
            for (int i = 0; i < NB_; i++) mx = fmaxf(mx, rec[n * NB_ + i]);
            float sm = 0.f;
            for (int i = 0; i < NB_; i++) { float e = expf(rec[n * NB_ + i] - mx); wsm[i] = e; sm += e; }
            float inv = 1.f / sm;
            for (int i = 0; i < NB_; i++) wsm[i] *= inv;
        }
        __syncthreads();
        if (threadIdx.x < NB_) sel[n * NB_ + threadIdx.x] = wsm[threadIdx.x];
        for (int d = threadIdx.x; d < D_; d += 256) {
            float acc = 0.f;
            #pragma unroll
            for (int nb = 0; nb < NB_; nb++) acc += wsm[nb] * bemb[nb * D_ + d];
            neb[(long)n * D_ + d] = __float2bfloat16(acc);
        }
    }
}

// ------------------------------------------------------------- final LN
__global__ __launch_bounds__(256) void ln_kernel(const float* __restrict__ in,
                                                 const float* __restrict__ g,
                                                 const float* __restrict__ b,
                                                 __hip_bfloat16* __restrict__ outb) {
    __shared__ float red[256];
    long t = blockIdx.x;
    ln_dev(in + t * D_, g, b, nullptr, outb, 512, t, red);
}

__global__ __launch_bounds__(64) void route_kernel(const float* __restrict__ scores,
                                                   const float* __restrict__ sel,
                                                   float* __restrict__ tr) {
    int t = blockIdx.x, lane = threadIdx.x;
    float myval = scores[(long)t * N_ + lane];
    float topv[K_]; int topi[K_];
    #pragma unroll
    for (int kk = 0; kk < K_; kk++) {
        float v = myval; int idx = lane;
        #pragma unroll
        for (int off = 32; off; off >>= 1) {
            float ov = __shfl_down(v, off);
            int oi = __shfl_down(idx, off);
            if (ov > v || (ov == v && oi < idx)) { v = ov; idx = oi; }
        }
        v = __shfl(v, 0); idx = __shfl(idx, 0);
        topv[kk] = v; topi[kk] = idx;
        if (lane == idx) myval = -INFINITY;
    }
    float mx = topv[0];
    float w[K_], sum = 0.f;
    #pragma unroll
    for (int kk = 0; kk < K_; kk++) { w[kk] = expf(topv[kk] - mx); sum += w[kk]; }
    float inv = 1.f / sum;
    if (lane < NB_) {
        float acc = 0.f;
        #pragma unroll
        for (int kk = 0; kk < K_; kk++) acc += w[kk] * inv * sel[topi[kk] * NB_ + lane];
        tr[(long)t * NB_ + lane] = acc;
    }
}

// h[r] = sum_n tr[n]*proj[t][n*64+r]; g[t][n*64+r] = bf16(tr[n]*h[r])
__global__ __launch_bounds__(256) void hg_kernel(const float* __restrict__ tr,
                                                 const float* __restrict__ P,
                                                 __hip_bfloat16* __restrict__ g) {
    int t = blockIdx.x, tid = threadIdx.x;
    __shared__ float hl[64];
    __shared__ float trl[32];
    if (tid < 32) trl[tid] = tr[(long)t * 32 + tid];
    __syncthreads();
    if (tid < 64) {
        float acc = 0.f;
        const float* p = P + (long)t * 2048 + tid;
        #pragma unroll
        for (int n = 0; n < 32; n++) acc += trl[n] * p[n * 64];
        hl[tid] = acc;
    }
    __syncthreads();
    #pragma unroll
    for (int j = 0; j < 8; j++) {
        int idx = tid * 8 + j;
        int n = idx >> 6, r = idx & 63;
        g[(long)t * 2048 + idx] = __float2bfloat16(trl[n] * hl[r]);
    }
}

// ------------------------------------------------------------- launch
extern "C" void kernel_launch(void* const* d_in, const int* in_sizes, int n_in,
                              void* d_out, int out_size, void* d_ws, size_t ws_size,
                              hipStream_t stream) {
    const int*   ids    = (const int*)d_in[0];
    const float* temb   = (const float*)d_in[1];
    const float* pemb   = (const float*)d_in[2];
    const float* basisA = (const float*)d_in[3];
    const float* bemb   = (const float*)d_in[4];
    const float* recipe = (const float*)d_in[5];
    const float* Wq = (const float*)d_in[6],  *bq = (const float*)d_in[7];
    const float* Wk = (const float*)d_in[8],  *bk = (const float*)d_in[9];
    const float* Wv = (const float*)d_in[10], *bv = (const float*)d_in[11];
    const float* Ws = (const float*)d_in[12], *bs = (const float*)d_in[13];
    const float* Wup = (const float*)d_in[14], *bup = (const float*)d_in[15];
    const float* Wdn = (const float*)d_in[16], *bdn = (const float*)d_in[17];
    const float* ln1g = (const float*)d_in[18], *ln1b = (const float*)d_in[19];
    const float* ln2g = (const float*)d_in[20], *ln2b = (const float*)d_in[21];
    const float* alpha = (const float*)d_in[22];
    const float* lnfg = (const float*)d_in[23], *lnfb = (const float*)d_in[24];
    float* out = (float*)d_out;
    float* W = (float*)d_ws;

    // fp32 arena (float offsets)
    float* x    = W + 0;          // 524288
    float* buf1 = W + 524288;     // n2 f32 (xf input)
    float* scb  = W + 1048576;    // scores 65536
    float* trb  = W + 1114112;    // 32768
    float* sel  = W + 1212416;    // 2048
    float* P    = W + 1214464;    // proj f32 2097152
    float* bqkv = W + 3835904;    // 6144
    // bf16 arena
    __hip_bfloat16* SB = (__hip_bfloat16*)(W + 3844096);
    __hip_bfloat16* tembB  = SB + 0;          // 16384000
    __hip_bfloat16* qkvT   = SB + 16384000;   // 3145728
    __hip_bfloat16* WsT    = SB + 19529728;   // 2097152
    __hip_bfloat16* WupT   = SB + 21626880;   // 4194304
    __hip_bfloat16* WdnT   = SB + 25821184;   // 4194304
    __hip_bfloat16* projT  = SB + 30015488;   // 1048576
    __hip_bfloat16* deltaT = SB + 31064064;   // 1048576
    __hip_bfloat16* neB    = SB + 32112640;   // 32768
    __hip_bfloat16* catB   = SB + 32145408;   // 1048576
    __hip_bfloat16* qryB   = SB + 33193984;   // 524288
    __hip_bfloat16* n2B    = SB + 33718272;   // 524288
    __hip_bfloat16* xfB    = SB + 34242560;   // 524288
    __hip_bfloat16* gB     = SB + 34766848;   // 2097152
    __hip_bfloat16* ffhB   = SB + 36864000;   // 2097152
    __hip_bfloat16* qkvB   = SB + 38961152;   // 1572864
    __hip_bfloat16* VtB    = SB + 40534016;   // 524288

    dim3 blk(256);
    // ---- merged one-time conversions + embed (1 launch) ----
    prologue_kernel<<<34456, blk, 0, stream>>>(
        temb, tembB, basisA, projT, deltaT, bq, bk, bv, bqkv,
        Wq, Wk, Wv, qkvT, Ws, WsT, Wup, WupT, Wdn, WdnT, ids, pemb, x);

    for (int l = 0; l < L_; l++) {
        // ln1 + ln2 + ne in one dispatch
        prep_kernel<<<2112, blk, 0, stream>>>(
            x, ln1g + l * D_, ln1b + l * D_, ln2g + l * D_, ln2b + l * D_,
            recipe + (long)l * N_ * NB_, bemb, catB, buf1, n2B, neB, sel);
        // fused QKV: [1024,1536] bf16 + V scatter into Vt
        gemm_mfma<64, 64, 2, 2, 5><<<dim3(24, 16), blk, 0, stream>>>(
            catB, 1024, 0, qkvT + (long)l * 1536 * 512, D_, 0, bqkv + l * 1536,
            (const float*)VtB, qkvB, 1536, 0, D_);
        attn_mfma<<<dim3(8, H_, B_), blk, 0, stream>>>(qkvB, VtB, catB);
        // query = cat @ Ws + bs -> bf16
        gemm_mfma<64, 64, 2, 2, 1><<<dim3(8, 16), blk, 0, stream>>>(
            catB, 2 * D_, 0, WsT + (long)l * 2 * D_ * D_, 2 * D_, 0, bs + l * D_, nullptr,
            qryB, D_, 0, 2 * D_);
        // scores = query @ ne^T (f32 out), then parallel top-k route
        gemm_mfma<128, 64, 2, 2, 0><<<dim3(1, 8), blk, 0, stream>>>(
            qryB, D_, 0, neB, D_, 0, nullptr, nullptr, scb, N_, 0, D_);
        route_kernel<<<T_, dim3(64), 0, stream>>>(scb, sel, trb);
        // proj: batched over n (z=32)
        gemm_mfma<128, 64, 2, 2, 0><<<dim3(1, 8, NB_), blk, 0, stream>>>(
            n2B, D_, 0, projT, D_, (long)R_ * D_, nullptr, nullptr, P, NB_ * R_, R_, D_);
        hg_kernel<<<T_, blk, 0, stream>>>(trb, P, gB);
        // delta GEMM + fused xf: xfB = bf16(n2 + alpha*delta)
        gemm_mfma<64, 64, 2, 2, 3><<<dim3(8, 16), blk, 0, stream>>>(
            gB, NB_ * R_, 0, deltaT, NB_ * R_, 0, alpha + l, buf1,
            xfB, D_, 0, NB_ * R_);
        // FFN up (+gelu, bf16 out)
        gemm_mfma<64, 64, 2, 2, 2><<<dim3(32, 16), blk, 0, stream>>>(
            xfB, D_, 0, WupT + (long)l * D_ * DFF_, D_, 0, bup + l * DFF_, nullptr,
            ffhB, DFF_, 0, D_);
        // FFN down fused residual: x += down + bias
        gemm_mfma<64, 64, 2, 2, 4><<<dim3(8, 16), blk, 0, stream>>>(
            ffhB, DFF_, 0, WdnT + (long)l * DFF_ * D_, DFF_, 0, bdn + l * D_, nullptr,
            x, D_, 0, DFF_);
    }
    // final LN + tied head (XCD-bijective swizzle, 2048 linear blocks)
    ln_kernel<<<T_, blk, 0, stream>>>(x, lnfg, lnfb, n2B);
    gemm_mfma<128, 128, 2, 2, 0, false, 1><<<dim3(2048), blk, 0, stream>>>(
        n2B, D_, 0, tembB, D_, 0, nullptr, nullptr, out, V_, 0, D_);
}